// Round 4
// baseline (13953.186 us; speedup 1.0000x reference)
//
#include <hip/hip_runtime.h>
#include <hip/hip_bf16.h>
#include <hip/hip_fp16.h>

#define Bn 256
#define Sn 128
#define Hn 512
#define G4 2048   // 4*H
#define BT 16     // batch tile per block
#define HT 16     // h tile per block

__device__ __forceinline__ float sigf(float x){
    float e = expf(-fabsf(x));
    float d = 1.f + e;
    return x >= 0.f ? 1.f/d : e/d;
}

// ---- rank-1 collapse of the input-side GEMMs (F_IN == 1) ----
// p1[j] = sum_k Wih[j,k]*We[k,0] ; p0[j] = sum_k Wih[j,k]*be[k] + b[j]
__global__ void precompute_kernel(
    const float* __restrict__ Wih_e, const float* __restrict__ We_e,
    const float* __restrict__ be_e,  const float* __restrict__ b_e,
    const float* __restrict__ Wih_d, const float* __restrict__ We_d,
    const float* __restrict__ be_d,  const float* __restrict__ b_d,
    float* __restrict__ p1, float* __restrict__ p0,
    float* __restrict__ r1, float* __restrict__ r0)
{
    int j = blockIdx.x*blockDim.x + threadIdx.x;   // 0..4095
    bool dec = j >= G4;
    int jj = dec ? j - G4 : j;
    const float* Wih = dec ? Wih_d : Wih_e;
    const float* We  = dec ? We_d  : We_e;
    const float* be  = dec ? be_d  : be_e;
    const float* bb  = dec ? b_d   : b_e;
    float s1 = 0.f, s0 = 0.f;
    for (int k = 0; k < Hn; ++k) {
        float w = Wih[jj*Hn + k];
        s1 += w * We[k];
        s0 += w * be[k];
    }
    s0 += bb[jj];
    if (dec) { r1[jj] = s1; r0[jj] = s0; }
    else     { p1[jj] = s1; p0[jj] = s0; }
}

// ---- one LSTM step: gates = gih + h_prev @ Whh^T, then elementwise ----
// MODE 0 (encoder): also emits w1enc[:, t-1, :] as a fused 5th dot vs W1
//                   (h_prev == enc_h[t-1] is already staged in LDS).
// MODE 1 (decoder): gih from x_in[b].
// WE_F32: w1enc element type (float when ws has room, else __half).
template<int MODE, bool WE_F32>
__global__ __launch_bounds__(256) void lstm_step_kernel(
    const float* __restrict__ h_prev,
    float* __restrict__ h_next,
    float* __restrict__ cbuf,
    const float* __restrict__ Whh,   // (4H, H)
    const float* __restrict__ P1,
    const float* __restrict__ P0,
    const float* __restrict__ xseq,  // MODE0: input_seq (B,S)
    const float* __restrict__ x_in,  // MODE1: (B,)
    const float* __restrict__ W1,    // MODE0: (H,H)
    const float* __restrict__ b1,    // MODE0
    void* __restrict__ w1enc,        // MODE0: (B,S,H)
    int t)
{
    __shared__ float hs[Hn][BT+1];   // padded: conflict-free both ways
    const int tid = threadIdx.x;
    const int b0 = blockIdx.x * BT;
    const int h0 = blockIdx.y * HT;
    const int lane_b = tid & (BT-1);
    const int hth = tid >> 4;        // 0..15

    for (int idx = tid; idx < BT*Hn; idx += 256) {
        int bb2 = idx >> 9;          // /Hn
        int k  = idx & (Hn-1);
        hs[k][bb2] = h_prev[(b0+bb2)*Hn + k];
    }
    __syncthreads();

    const int hg = h0 + hth;
    constexpr int NACC = (MODE==0) ? 5 : 4;
    float acc[NACC];
    #pragma unroll
    for (int g = 0; g < NACC; ++g) acc[g] = 0.f;
    const float* wrow[NACC];
    #pragma unroll
    for (int g = 0; g < 4; ++g) wrow[g] = Whh + (size_t)(g*Hn + hg)*Hn;
    if constexpr (MODE == 0) wrow[4] = W1 + (size_t)hg*Hn;

    for (int k = 0; k < Hn; k += 8) {
        float hv[8];
        #pragma unroll
        for (int j = 0; j < 8; ++j) hv[j] = hs[k+j][lane_b];
        #pragma unroll
        for (int g = 0; g < NACC; ++g) {
            float4 wa = *(const float4*)(wrow[g] + k);
            float4 wb = *(const float4*)(wrow[g] + k + 4);
            acc[g] += hv[0]*wa.x + hv[1]*wa.y + hv[2]*wa.z + hv[3]*wa.w
                    + hv[4]*wb.x + hv[5]*wb.y + hv[6]*wb.z + hv[7]*wb.w;
        }
    }

    const int b_glob = b0 + lane_b;
    float xv = (MODE==0) ? xseq[b_glob*Sn + t] : x_in[b_glob];
    float gi = acc[0] + xv*P1[0*Hn+hg] + P0[0*Hn+hg];
    float gf = acc[1] + xv*P1[1*Hn+hg] + P0[1*Hn+hg];
    float gg = acc[2] + xv*P1[2*Hn+hg] + P0[2*Hn+hg];
    float go = acc[3] + xv*P1[3*Hn+hg] + P0[3*Hn+hg];
    size_t off = (size_t)b_glob*Hn + hg;
    float cold = cbuf[off];
    float cn = sigf(gf)*cold + sigf(gi)*tanhf(gg);
    float hn = sigf(go)*tanhf(cn);
    cbuf[off] = cn;
    h_next[off] = hn;
    if constexpr (MODE == 0) {
        if (t > 0) {
            size_t widx = (size_t)b_glob*(Sn*Hn) + (size_t)(t-1)*Hn + hg;
            float val = acc[4] + b1[hg];
            if constexpr (WE_F32) ((float*)w1enc)[widx] = val;
            else                  ((__half*)w1enc)[widx] = __float2half(val);
        }
    }
}

// ---- out[b*ostride + ooff + n] = h @ W^T + bias ----
template<bool OF32>
__global__ __launch_bounds__(256) void linear_kernel(
    const float* __restrict__ hin,
    const float* __restrict__ W,     // (H,H)
    const float* __restrict__ bias,
    void* __restrict__ outp,
    int ostride, int ooff)
{
    __shared__ float hs[Hn][BT+1];
    const int tid = threadIdx.x;
    const int b0 = blockIdx.x * BT;
    const int n0 = blockIdx.y * HT;
    const int lane_b = tid & (BT-1);
    const int hth = tid >> 4;
    for (int idx = tid; idx < BT*Hn; idx += 256) {
        int bb2 = idx >> 9;
        int k  = idx & (Hn-1);
        hs[k][bb2] = hin[(b0+bb2)*Hn + k];
    }
    __syncthreads();
    const int ng = n0 + hth;
    const float* wr = W + (size_t)ng*Hn;
    float acc = 0.f;
    for (int k = 0; k < Hn; k += 8) {
        float4 wa = *(const float4*)(wr + k);
        float4 wb = *(const float4*)(wr + k + 4);
        acc += hs[k+0][lane_b]*wa.x + hs[k+1][lane_b]*wa.y
             + hs[k+2][lane_b]*wa.z + hs[k+3][lane_b]*wa.w
             + hs[k+4][lane_b]*wb.x + hs[k+5][lane_b]*wb.y
             + hs[k+6][lane_b]*wb.z + hs[k+7][lane_b]*wb.w;
    }
    float val = acc + bias[ng];
    size_t oidx = (size_t)(b0+lane_b)*ostride + ooff + ng;
    if constexpr (OF32) ((float*)outp)[oidx] = val;
    else                ((__half*)outp)[oidx] = __float2half(val);
}

// ---- attention + log_softmax + argmax + pointer feedback, one block per b ----
template<bool WE_F32>
__global__ __launch_bounds__(512) void attn_kernel(
    const void* __restrict__ w1enc,    // (B,S,H)
    const float* __restrict__ q,       // (B,H) f32
    const float* __restrict__ v,
    const float* __restrict__ xseq,
    float* __restrict__ out_scores,    // (B,S,S) f32
    float* __restrict__ out_ptr,       // (B,S) f32 (pointer indices as floats)
    float* __restrict__ x_in,          // (B,)
    int t)
{
    __shared__ float qs[Hn], vs[Hn], us[Sn], red[2];
    const int b = blockIdx.x;
    const int tid = threadIdx.x;
    if (tid < Hn) { qs[tid] = q[b*Hn + tid]; vs[tid] = v[tid]; }
    __syncthreads();
    const int wave = tid >> 6, l = tid & 63;
    const int sub = l >> 5, kl = l & 31;
    const int k0 = kl*16;
    for (int si = 0; si < 8; ++si) {
        int s = si*16 + wave*2 + sub;
        float w[16];
        if constexpr (WE_F32) {
            const float* wr = (const float*)w1enc + ((size_t)b*Sn + s)*Hn + k0;
            #pragma unroll
            for (int i = 0; i < 16; i += 4) {
                float4 wv = *(const float4*)(wr + i);
                w[i+0]=wv.x; w[i+1]=wv.y; w[i+2]=wv.z; w[i+3]=wv.w;
            }
        } else {
            const __half* wr = (const __half*)w1enc + ((size_t)b*Sn + s)*Hn + k0;
            #pragma unroll
            for (int i = 0; i < 16; i += 8) {
                uint4 u = *(const uint4*)(wr + i);
                float2 f0 = __half22float2(*(const __half2*)&u.x);
                float2 f1 = __half22float2(*(const __half2*)&u.y);
                float2 f2 = __half22float2(*(const __half2*)&u.z);
                float2 f3 = __half22float2(*(const __half2*)&u.w);
                w[i+0]=f0.x; w[i+1]=f0.y; w[i+2]=f1.x; w[i+3]=f1.y;
                w[i+4]=f2.x; w[i+5]=f2.y; w[i+6]=f3.x; w[i+7]=f3.y;
            }
        }
        float a = 0.f;
        #pragma unroll
        for (int i = 0; i < 16; ++i)
            a += vs[k0+i]*tanhf(w[i] + qs[k0+i]);
        #pragma unroll
        for (int off2 = 1; off2 <= 16; off2 <<= 1) a += __shfl_xor(a, off2);
        if (kl == 0) us[s] = a;
    }
    __syncthreads();
    if (wave == 0) {
        float a = us[l], c2 = us[l+64];
        float mv; int mi;
        if (c2 > a) { mv = c2; mi = l+64; } else { mv = a; mi = l; }  // tie -> first
        #pragma unroll
        for (int off2 = 1; off2 < 64; off2 <<= 1) {
            float ov = __shfl_xor(mv, off2);
            int   oi = __shfl_xor(mi, off2);
            if (ov > mv || (ov == mv && oi < mi)) { mv = ov; mi = oi; }
        }
        float es = expf(a - mv) + expf(c2 - mv);
        #pragma unroll
        for (int off2 = 1; off2 < 64; off2 <<= 1) es += __shfl_xor(es, off2);
        if (l == 0) {
            red[0] = mv; red[1] = logf(es);
            out_ptr[b*Sn + t] = (float)mi;
            x_in[b] = xseq[b*Sn + mi];   // next decoder input symbol
        }
    }
    __syncthreads();
    if (tid < Sn) {
        out_scores[(size_t)b*Sn*Sn + (size_t)t*Sn + tid] =
            us[tid] - red[0] - red[1];
    }
}

extern "C" void kernel_launch(void* const* d_in, const int* in_sizes, int n_in,
                              void* d_out, int out_size, void* d_ws, size_t ws_size,
                              hipStream_t stream)
{
    const float* input_seq = (const float*)d_in[0];
    const float* We_e = (const float*)d_in[1],  *be_e = (const float*)d_in[2];
    const float* Wih_e = (const float*)d_in[3], *Whh_e = (const float*)d_in[4];
    const float* b_e = (const float*)d_in[5];
    const float* We_d = (const float*)d_in[6],  *be_d = (const float*)d_in[7];
    const float* Wih_d = (const float*)d_in[8], *Whh_d = (const float*)d_in[9];
    const float* b_d = (const float*)d_in[10];
    const float* W1 = (const float*)d_in[11], *b1 = (const float*)d_in[12];
    const float* W2 = (const float*)d_in[13], *b2 = (const float*)d_in[14];
    const float* v  = (const float*)d_in[15];  // bv (d_in[16]) cancels in log_softmax

    float* ws = (float*)d_ws;
    size_t o = 0;
    float* hb0  = ws + o; o += Bn*Hn;
    float* hb1  = ws + o; o += Bn*Hn;
    float* cbuf = ws + o; o += Bn*Hn;
    float* qbuf = ws + o; o += Bn*Hn;
    float* p1   = ws + o; o += G4;
    float* p0   = ws + o; o += G4;
    float* r1   = ws + o; o += G4;
    float* r0   = ws + o; o += G4;
    float* x_in = ws + o; o += 256;
    void* w1enc = (void*)(ws + o);
    const size_t w1enc_elems = (size_t)Bn*Sn*Hn;               // 16.8M
    const size_t need_f32 = (o + w1enc_elems) * sizeof(float); // ~69.2 MB
    const bool wf32 = (ws_size >= need_f32);

    hipMemsetAsync(hb0,  0, Bn*Hn*sizeof(float), stream);
    hipMemsetAsync(cbuf, 0, Bn*Hn*sizeof(float), stream);
    hipMemsetAsync(x_in, 0, Bn*sizeof(float), stream);

    precompute_kernel<<<dim3(16), 256, 0, stream>>>(Wih_e, We_e, be_e, b_e,
                                                    Wih_d, We_d, be_d, b_d,
                                                    p1, p0, r1, r0);

    dim3 gtile(Bn/BT, Hn/HT);   // 16 x 32 = 512 blocks
    float* hprev = hb0; float* hnext = hb1;
    for (int t = 0; t < Sn; ++t) {
        if (wf32)
            lstm_step_kernel<0,true ><<<gtile, 256, 0, stream>>>(hprev, hnext, cbuf, Whh_e,
                                                                 p1, p0, input_seq, nullptr,
                                                                 W1, b1, w1enc, t);
        else
            lstm_step_kernel<0,false><<<gtile, 256, 0, stream>>>(hprev, hnext, cbuf, Whh_e,
                                                                 p1, p0, input_seq, nullptr,
                                                                 W1, b1, w1enc, t);
        float* tmp = hprev; hprev = hnext; hnext = tmp;
    }
    // last row of w1enc from final encoder h
    if (wf32)
        linear_kernel<true ><<<gtile, 256, 0, stream>>>(hprev, W1, b1, w1enc,
                                                        Sn*Hn, (Sn-1)*Hn);
    else
        linear_kernel<false><<<gtile, 256, 0, stream>>>(hprev, W1, b1, w1enc,
                                                        Sn*Hn, (Sn-1)*Hn);

    float* out_scores = (float*)d_out;                       // (B,S,S) f32
    float* out_ptr = out_scores + (size_t)Bn*Sn*Sn;          // (B,S) f32

    for (int t = 0; t < Sn; ++t) {
        if (wf32) {
            lstm_step_kernel<1,true ><<<gtile, 256, 0, stream>>>(hprev, hnext, cbuf, Whh_d,
                                                                 r1, r0, nullptr, x_in,
                                                                 nullptr, nullptr, nullptr, t);
            linear_kernel<true ><<<gtile, 256, 0, stream>>>(hnext, W2, b2, qbuf, Hn, 0);
            attn_kernel<true ><<<dim3(Bn), 512, 0, stream>>>(w1enc, qbuf, v, input_seq,
                                                             out_scores, out_ptr, x_in, t);
        } else {
            lstm_step_kernel<1,false><<<gtile, 256, 0, stream>>>(hprev, hnext, cbuf, Whh_d,
                                                                 r1, r0, nullptr, x_in,
                                                                 nullptr, nullptr, nullptr, t);
            linear_kernel<true ><<<gtile, 256, 0, stream>>>(hnext, W2, b2, qbuf, Hn, 0);
            attn_kernel<false><<<dim3(Bn), 512, 0, stream>>>(w1enc, qbuf, v, input_seq,
                                                             out_scores, out_ptr, x_in, t);
        }
        float* tmp = hprev; hprev = hnext; hnext = tmp;
    }
}